// Round 6
// baseline (389.487 us; speedup 1.0000x reference)
//
#include <hip/hip_runtime.h>

#define NN 100000
#define EE 1600000
#define IND 512
#define HIDD 128
#define OUTD 16
#define DEG_BLKS 128
#define GEMM_BLKS 782  // ceil(NN/128)

typedef __bf16 bf16x8 __attribute__((ext_vector_type(8)));
typedef float f32x4 __attribute__((ext_vector_type(4)));

__device__ __forceinline__ ushort f2bf(float f) {
    union { float f; uint u; } v; v.f = f;
    uint r = v.u + 0x7FFFu + ((v.u >> 16) & 1u);
    return (ushort)(r >> 16);
}

// ---------------- W prep: both layers in one launch ----------------
__global__ void k_prep(const float* __restrict__ W1, const float* __restrict__ W2,
                       ushort* __restrict__ Wt1, ushort* __restrict__ Wt2) {
    int b = blockIdx.x, tid = threadIdx.x;
    if (b < 256) {  // W1: 512x128 -> Wt1[128][512]
        int i = b * 256 + tid;
        int k = i >> 7, n = i & 127;
        Wt1[n * 512 + k] = f2bf(W1[i]);
    } else {        // W2: 128x128 -> Wt2[128][128]
        int i = (b - 256) * 256 + tid;
        int k = i >> 7, n = i & 127;
        Wt2[n * 128 + k] = f2bf(W2[i]);
    }
}

// ---------------- scan (3 phases; norm fused into final) ----------------
__global__ void k_scan_local(const int* __restrict__ deg, int* __restrict__ incl,
                             int* __restrict__ bsum) {
    __shared__ int s[256];
    int tid = threadIdx.x;
    int i = blockIdx.x * 256 + tid;
    int v = (i < NN) ? deg[i] : 0;
    s[tid] = v;
    __syncthreads();
    for (int off = 1; off < 256; off <<= 1) {
        int t = (tid >= off) ? s[tid - off] : 0;
        __syncthreads();
        s[tid] += t;
        __syncthreads();
    }
    if (i < NN) incl[i] = s[tid];
    if (tid == 255) bsum[blockIdx.x] = s[255];
}

__global__ void k_scan_bsum(const int* __restrict__ bsum, int* __restrict__ boff, int n) {
    __shared__ int s[512];
    int tid = threadIdx.x;
    int v = (tid < n) ? bsum[tid] : 0;
    s[tid] = v;
    __syncthreads();
    for (int off = 1; off < 512; off <<= 1) {
        int t = (tid >= off) ? s[tid - off] : 0;
        __syncthreads();
        s[tid] += t;
        __syncthreads();
    }
    if (tid < n) boff[tid] = s[tid] - v;  // exclusive
}

__global__ void k_scan_final(const int* __restrict__ incl, const int* __restrict__ deg,
                             const int* __restrict__ boff, int* __restrict__ rs,
                             int* __restrict__ cursor, float* __restrict__ dis,
                             float* __restrict__ dinv) {
    int i = blockIdx.x * 256 + threadIdx.x;
    if (i < NN) {
        int d = deg[i];
        int v = incl[i] + boff[i >> 8];  // global inclusive
        int start = v - d;
        rs[i] = start;
        cursor[i] = start;
        if (i == NN - 1) rs[NN] = v;  // == EE
        float df = (float)(d + 1);
        dis[i] = rsqrtf(df);
        dinv[i] = 1.0f / df;
    }
}

// ---------------- CSR fill: (src, weight) pairs ----------------
__global__ void k_fill(const int* __restrict__ src, const int* __restrict__ dst,
                       const float* __restrict__ dis, int* __restrict__ cursor,
                       int2* __restrict__ ew) {
    int i = blockIdx.x * blockDim.x + threadIdx.x;
    int stride = gridDim.x * blockDim.x;
    for (; i < EE; i += stride) {
        int d = dst[i];
        int s = src[i];
        int pos = atomicAdd(&cursor[d], 1);
        ew[pos] = make_int2(s, __float_as_int(dis[s] * dis[d]));
    }
}

// ---------------- bf16 MFMA GEMM body: C[M][128] = A[M][K] @ W[K][128] ----------------
// BM=128, BK=32, 4 waves; wave w -> rows [w*32, w*32+32), all 128 cols.
// Register-prefetch pipeline: issue tile k+1 loads, MFMA tile k, sync, LDS-write, sync.
template <int K, bool AFP32>
__device__ __forceinline__ void gemm_body(const void* __restrict__ Ap,
                                          const ushort* __restrict__ Wt,
                                          ushort* __restrict__ C, int M, int blk) {
    __shared__ ushort As[128][40];  // [m][k], padded (80B rows)
    __shared__ ushort Ws[128][40];  // [n][k]
    int tid = threadIdx.x;
    int row0 = blk * 128;
    int wid = tid >> 6, lane = tid & 63;
    int wm = wid * 32;
    int lm = lane & 15, lk8 = (lane >> 4) * 8;

    // staging roles: 2 threads per row, 16 k-elems each
    int srow = tid >> 1;
    int koff = (tid & 1) * 16;
    int arow = row0 + srow;
    if (arow >= M) arow = M - 1;  // clamp: garbage rows never stored
    const float* Af = (const float*)Ap;
    const ushort* Ab = (const ushort*)Ap;
    const ushort* Wrow = Wt + (size_t)srow * K + koff;

    f32x4 acc[8][2];
#pragma unroll
    for (int q = 0; q < 8; q++)
#pragma unroll
        for (int r = 0; r < 2; r++) acc[q][r] = (f32x4){0.f, 0.f, 0.f, 0.f};

    float4 a0, a1, a2, a3;  // fp32 A staging
    uint4 ab0, ab1;         // bf16 A staging
    uint4 w0, w1;           // W staging

#define G_LOAD(k0)                                                  \
    {                                                               \
        if (AFP32) {                                                \
            const float* p = Af + (size_t)arow * K + (k0) + koff;   \
            a0 = *(const float4*)(p);                               \
            a1 = *(const float4*)(p + 4);                           \
            a2 = *(const float4*)(p + 8);                           \
            a3 = *(const float4*)(p + 12);                          \
        } else {                                                    \
            const ushort* p = Ab + (size_t)arow * K + (k0) + koff;  \
            ab0 = *(const uint4*)(p);                               \
            ab1 = *(const uint4*)(p + 8);                           \
        }                                                           \
        const ushort* q_ = Wrow + (k0);                             \
        w0 = *(const uint4*)(q_);                                   \
        w1 = *(const uint4*)(q_ + 8);                               \
    }

#define L_STORE()                                                   \
    {                                                               \
        if (AFP32) {                                                \
            uint4 pk0, pk1;                                         \
            pk0.x = (uint)f2bf(a0.x) | ((uint)f2bf(a0.y) << 16);    \
            pk0.y = (uint)f2bf(a0.z) | ((uint)f2bf(a0.w) << 16);    \
            pk0.z = (uint)f2bf(a1.x) | ((uint)f2bf(a1.y) << 16);    \
            pk0.w = (uint)f2bf(a1.z) | ((uint)f2bf(a1.w) << 16);    \
            pk1.x = (uint)f2bf(a2.x) | ((uint)f2bf(a2.y) << 16);    \
            pk1.y = (uint)f2bf(a2.z) | ((uint)f2bf(a2.w) << 16);    \
            pk1.z = (uint)f2bf(a3.x) | ((uint)f2bf(a3.y) << 16);    \
            pk1.w = (uint)f2bf(a3.z) | ((uint)f2bf(a3.w) << 16);    \
            *(uint4*)&As[srow][koff] = pk0;                         \
            *(uint4*)&As[srow][koff + 8] = pk1;                     \
        } else {                                                    \
            *(uint4*)&As[srow][koff] = ab0;                         \
            *(uint4*)&As[srow][koff + 8] = ab1;                     \
        }                                                           \
        *(uint4*)&Ws[srow][koff] = w0;                              \
        *(uint4*)&Ws[srow][koff + 8] = w1;                          \
    }

    G_LOAD(0)
    L_STORE()
    __syncthreads();

    for (int k0 = 0; k0 < K; k0 += 32) {
        bool notlast = (k0 + 32 < K);
        if (notlast) G_LOAD(k0 + 32)  // in flight across MFMA phase

        bf16x8 xf[2], wf[8];
#pragma unroll
        for (int r = 0; r < 2; r++) xf[r] = *(const bf16x8*)&As[wm + r * 16 + lm][lk8];
#pragma unroll
        for (int q = 0; q < 8; q++) wf[q] = *(const bf16x8*)&Ws[q * 16 + lm][lk8];
#pragma unroll
        for (int q = 0; q < 8; q++)
#pragma unroll
            for (int r = 0; r < 2; r++)
                acc[q][r] = __builtin_amdgcn_mfma_f32_16x16x32_bf16(wf[q], xf[r], acc[q][r], 0, 0, 0);

        if (notlast) {
            __syncthreads();
            L_STORE()
            __syncthreads();
        }
    }
#undef G_LOAD
#undef L_STORE

    int cn4 = (lane >> 4) * 4;
#pragma unroll
    for (int r = 0; r < 2; r++) {
        int m = row0 + wm + r * 16 + lm;
        if (m < M) {
#pragma unroll
            for (int q = 0; q < 8; q++) {
                int n = q * 16 + cn4;
                uint2 o;
                o.x = (uint)f2bf(acc[q][r][0]) | ((uint)f2bf(acc[q][r][1]) << 16);
                o.y = (uint)f2bf(acc[q][r][2]) | ((uint)f2bf(acc[q][r][3]) << 16);
                *(uint2*)(C + (size_t)m * 128 + n) = o;
            }
        }
    }
}

// mega kernel 1: blocks [0,DEG_BLKS) count degrees; rest do GEMM1
__global__ __launch_bounds__(256) void k_mega1(const float* __restrict__ x,
                                               const ushort* __restrict__ Wt1,
                                               ushort* __restrict__ C,
                                               const int* __restrict__ dst,
                                               int* __restrict__ deg) {
    if (blockIdx.x < DEG_BLKS) {
        int i = blockIdx.x * 256 + threadIdx.x;
        int stride = DEG_BLKS * 256;
        for (; i < EE; i += stride) atomicAdd(&deg[dst[i]], 1);
    } else {
        gemm_body<IND, true>(x, Wt1, C, NN, blockIdx.x - DEG_BLKS);
    }
}

__global__ __launch_bounds__(256) void k_gemm2(const ushort* __restrict__ A,
                                               const ushort* __restrict__ Wt,
                                               ushort* __restrict__ C) {
    gemm_body<HIDD, false>(A, Wt, C, NN, blockIdx.x);
}

// ---------------- aggregation over bf16 h ----------------
// One node per wave. Half-wave edge pairing: lanes 0-31 even edges, 32-63 odd;
// each lane loads uint2 (4 dims), 32 lanes cover the 128-dim row.
template <bool OUTF32>
__global__ __launch_bounds__(256) void k_agg(const ushort* __restrict__ h,
                                             const int* __restrict__ rs,
                                             const int2* __restrict__ ew,
                                             const float* __restrict__ dinv,
                                             const float* __restrict__ bias,
                                             void* __restrict__ yv) {
    int node = blockIdx.x * 4 + (threadIdx.x >> 6);
    int lane = threadIdx.x & 63;
    if (node >= NN) return;
    int half = lane >> 5, c = lane & 31;
    const uint2* h64 = (const uint2*)h;

    float acc0 = 0.f, acc1 = 0.f, acc2 = 0.f, acc3 = 0.f;
    if (half == 0) {  // self-loop term, lower half only
        float dv = dinv[node];
        uint2 sv = h64[(size_t)node * 32 + c];
        acc0 = __uint_as_float(sv.x << 16) * dv;
        acc1 = __uint_as_float(sv.x & 0xffff0000u) * dv;
        acc2 = __uint_as_float(sv.y << 16) * dv;
        acc3 = __uint_as_float(sv.y & 0xffff0000u) * dv;
    }

    int e = rs[node], e1 = rs[node + 1];

#define EL(i) int2 p##i = ew[e + 2 * i + half]; \
              uint2 g##i = h64[(size_t)(uint)p##i.x * 32 + c];
#define EA(i) { float w##i = __int_as_float(p##i.y); \
    acc0 += w##i * __uint_as_float(g##i.x << 16); \
    acc1 += w##i * __uint_as_float(g##i.x & 0xffff0000u); \
    acc2 += w##i * __uint_as_float(g##i.y << 16); \
    acc3 += w##i * __uint_as_float(g##i.y & 0xffff0000u); }

    for (; e + 16 <= e1; e += 16) {  // 8 pairs = 16 edges in flight
        EL(0) EL(1) EL(2) EL(3) EL(4) EL(5) EL(6) EL(7)
        EA(0) EA(1) EA(2) EA(3) EA(4) EA(5) EA(6) EA(7)
    }
    for (; e + 4 <= e1; e += 4) {    // 2 pairs = 4 edges
        EL(0) EL(1)
        EA(0) EA(1)
    }
    if (e + 2 <= e1) {               // 1 pair
        EL(0)
        EA(0)
        e += 2;
    }
    if (e < e1 && half == 0) {       // final odd edge, lower half only
        int2 p = ew[e];
        uint2 g = h64[(size_t)(uint)p.x * 32 + c];
        float w = __int_as_float(p.y);
        acc0 += w * __uint_as_float(g.x << 16);
        acc1 += w * __uint_as_float(g.x & 0xffff0000u);
        acc2 += w * __uint_as_float(g.y << 16);
        acc3 += w * __uint_as_float(g.y & 0xffff0000u);
    }
#undef EL
#undef EA

    // merge halves
    acc0 += __shfl_xor(acc0, 32, 64);
    acc1 += __shfl_xor(acc1, 32, 64);
    acc2 += __shfl_xor(acc2, 32, 64);
    acc3 += __shfl_xor(acc3, 32, 64);

    if (half == 0) {
        float4 bv = *(const float4*)(bias + c * 4);
        acc0 = fmaxf(acc0 + bv.x, 0.f);
        acc1 = fmaxf(acc1 + bv.y, 0.f);
        acc2 = fmaxf(acc2 + bv.z, 0.f);
        acc3 = fmaxf(acc3 + bv.w, 0.f);
        if (OUTF32) {
            *(float4*)((float*)yv + (size_t)node * 128 + c * 4) =
                make_float4(acc0, acc1, acc2, acc3);
        } else {
            uint2 o;
            o.x = (uint)f2bf(acc0) | ((uint)f2bf(acc1) << 16);
            o.y = (uint)f2bf(acc2) | ((uint)f2bf(acc3) << 16);
            *(uint2*)((ushort*)yv + (size_t)node * 128 + c * 4) = o;
        }
    }
}

// ---------------- head: out[N][16] = emb[N][128] @ Wl[128][16] + bl ----------------
__global__ __launch_bounds__(256) void k_out(const float* __restrict__ emb,
                                             const float* __restrict__ Wl,
                                             const float* __restrict__ bl,
                                             float* __restrict__ out) {
    __shared__ float wl_s[128 * 16];
    __shared__ float es[16][129];
    int tid = threadIdx.x;
    int row0 = blockIdx.x * 16;
#pragma unroll
    for (int p = 0; p < 8; p++) wl_s[p * 256 + tid] = Wl[p * 256 + tid];
#pragma unroll
    for (int p = 0; p < 8; p++) {
        int idx = p * 256 + tid;
        int r = idx >> 7, c = idx & 127;
        int gr = row0 + r;
        es[r][c] = (gr < NN) ? emb[(size_t)gr * 128 + c] : 0.0f;
    }
    __syncthreads();
    int r = tid >> 4, o = tid & 15;
    float acc = bl[o];
#pragma unroll
    for (int k = 0; k < 128; k++) acc += es[r][k] * wl_s[k * 16 + o];
    int gr = row0 + r;
    if (gr < NN) out[(size_t)gr * 16 + o] = acc;
}

extern "C" void kernel_launch(void* const* d_in, const int* in_sizes, int n_in,
                              void* d_out, int out_size, void* d_ws, size_t ws_size,
                              hipStream_t stream) {
    const float* x  = (const float*)d_in[0];
    const int* ei   = (const int*)d_in[1];  // [2][E]: row0=src, row1=dst
    const float* W1 = (const float*)d_in[2];
    const float* b1 = (const float*)d_in[3];
    const float* W2 = (const float*)d_in[4];
    const float* b2 = (const float*)d_in[5];
    const float* Wl = (const float*)d_in[6];
    const float* bl = (const float*)d_in[7];
    const int* src = ei;
    const int* dst = ei + EE;

    float* outp = (float*)d_out;             // [N][16]
    float* emb  = outp + (size_t)NN * OUTD;  // [N][128] fp32

    int2* ew    = (int2*)d_ws;                        // E pairs (src, w)
    ushort* h_a = (ushort*)(ew + EE);                 // N*128 bf16
    ushort* h_b = h_a + (size_t)NN * 128;             // N*128 bf16
    ushort* Wt1 = h_b + (size_t)NN * 128;             // 128*512 bf16
    ushort* Wt2 = Wt1 + 128 * 512;                    // 128*128 bf16
    int* deg    = (int*)(Wt2 + 128 * 128);
    float* dis  = (float*)(deg + NN);
    float* dinv = dis + NN;
    int* incl   = (int*)(dinv + NN);
    int* rs     = incl + NN;                          // N+1
    int* cursor = rs + NN + 8;
    int* bsum   = cursor + NN;
    int* boff   = bsum + 512;

    const int NB_N = (NN + 255) / 256;  // 391

    hipMemsetAsync(deg, 0, (size_t)NN * sizeof(int), stream);
    k_prep<<<320, 256, 0, stream>>>(W1, W2, Wt1, Wt2);
    // gemm1 (x@W1 -> h_a bf16)  ||  degree count
    k_mega1<<<DEG_BLKS + GEMM_BLKS, 256, 0, stream>>>(x, Wt1, h_a, dst, deg);
    k_scan_local<<<NB_N, 256, 0, stream>>>(deg, incl, bsum);
    k_scan_bsum<<<1, 512, 0, stream>>>(bsum, boff, NB_N);
    k_scan_final<<<NB_N, 256, 0, stream>>>(incl, deg, boff, rs, cursor, dis, dinv);
    k_fill<<<2048, 256, 0, stream>>>(src, dst, dis, cursor, ew);

    // layer 1 agg: h_b = bf16(relu(agg(h_a) + b1))
    k_agg<false><<<(NN + 3) / 4, 256, 0, stream>>>(h_a, rs, ew, dinv, b1, h_b);
    // layer 2: h_a = bf16(h_b @ W2); emb = fp32(relu(agg(h_a) + b2))
    k_gemm2<<<GEMM_BLKS, 256, 0, stream>>>(h_b, Wt2, h_a);
    k_agg<true><<<(NN + 3) / 4, 256, 0, stream>>>(h_a, rs, ew, dinv, b2, emb);
    // head
    k_out<<<(NN + 15) / 16, 256, 0, stream>>>(emb, Wl, bl, outp);
}

// Round 7
// 376.779 us; speedup vs baseline: 1.0337x; 1.0337x over previous
//
#include <hip/hip_runtime.h>

#define NN 100000
#define EE 1600000
#define IND 512
#define HIDD 128
#define OUTD 16
#define DEG_BLKS 128
#define GEMM_BLKS 782  // ceil(NN/128)

typedef __bf16 bf16x8 __attribute__((ext_vector_type(8)));
typedef float f32x4 __attribute__((ext_vector_type(4)));

__device__ __forceinline__ ushort f2bf(float f) {
    union { float f; uint u; } v; v.f = f;
    uint r = v.u + 0x7FFFu + ((v.u >> 16) & 1u);
    return (ushort)(r >> 16);
}

// packed f32x2 -> bf16x2 (RNE via hardware cvt)
__device__ __forceinline__ uint pk2bf(float a, float b) {
    __bf16 x = (__bf16)a, y = (__bf16)b;
    ushort ux = *(ushort*)&x, uy = *(ushort*)&y;
    return (uint)ux | ((uint)uy << 16);
}

#define GLDS16(src, dst)                                              \
    __builtin_amdgcn_global_load_lds(                                 \
        (const __attribute__((address_space(1))) void*)(src),         \
        (__attribute__((address_space(3))) void*)(dst), 16, 0, 0)

// ---------------- W prep: both layers in one launch ----------------
__global__ void k_prep(const float* __restrict__ W1, const float* __restrict__ W2,
                       ushort* __restrict__ Wt1, ushort* __restrict__ Wt2) {
    int b = blockIdx.x, tid = threadIdx.x;
    if (b < 256) {  // W1: 512x128 -> Wt1[128][512]
        int i = b * 256 + tid;
        int k = i >> 7, n = i & 127;
        Wt1[n * 512 + k] = f2bf(W1[i]);
    } else {        // W2: 128x128 -> Wt2[128][128]
        int i = (b - 256) * 256 + tid;
        int k = i >> 7, n = i & 127;
        Wt2[n * 128 + k] = f2bf(W2[i]);
    }
}

// ---------------- scan (3 phases; norm fused into final) ----------------
__global__ void k_scan_local(const int* __restrict__ deg, int* __restrict__ incl,
                             int* __restrict__ bsum) {
    __shared__ int s[256];
    int tid = threadIdx.x;
    int i = blockIdx.x * 256 + tid;
    int v = (i < NN) ? deg[i] : 0;
    s[tid] = v;
    __syncthreads();
    for (int off = 1; off < 256; off <<= 1) {
        int t = (tid >= off) ? s[tid - off] : 0;
        __syncthreads();
        s[tid] += t;
        __syncthreads();
    }
    if (i < NN) incl[i] = s[tid];
    if (tid == 255) bsum[blockIdx.x] = s[255];
}

__global__ void k_scan_bsum(const int* __restrict__ bsum, int* __restrict__ boff, int n) {
    __shared__ int s[512];
    int tid = threadIdx.x;
    int v = (tid < n) ? bsum[tid] : 0;
    s[tid] = v;
    __syncthreads();
    for (int off = 1; off < 512; off <<= 1) {
        int t = (tid >= off) ? s[tid - off] : 0;
        __syncthreads();
        s[tid] += t;
        __syncthreads();
    }
    if (tid < n) boff[tid] = s[tid] - v;  // exclusive
}

__global__ void k_scan_final(const int* __restrict__ incl, const int* __restrict__ deg,
                             const int* __restrict__ boff, int* __restrict__ rs,
                             int* __restrict__ cursor, float* __restrict__ dis,
                             float* __restrict__ dinv) {
    int i = blockIdx.x * 256 + threadIdx.x;
    if (i < NN) {
        int d = deg[i];
        int v = incl[i] + boff[i >> 8];  // global inclusive
        int start = v - d;
        rs[i] = start;
        cursor[i] = start;
        if (i == NN - 1) rs[NN] = v;  // == EE
        float df = (float)(d + 1);
        dis[i] = rsqrtf(df);
        dinv[i] = 1.0f / df;
    }
}

// ---------------- CSR fill: (src, weight) pairs ----------------
__global__ void k_fill(const int* __restrict__ src, const int* __restrict__ dst,
                       const float* __restrict__ dis, int* __restrict__ cursor,
                       int2* __restrict__ ew) {
    int i = blockIdx.x * blockDim.x + threadIdx.x;
    int stride = gridDim.x * blockDim.x;
    for (; i < EE; i += stride) {
        int d = dst[i];
        int s = src[i];
        int pos = atomicAdd(&cursor[d], 1);
        ew[pos] = make_int2(s, __float_as_int(dis[s] * dis[d]));
    }
}

// ---------------- bf16 MFMA GEMM body: C[M][128] = A[M][K] @ W[K][128] ----------------
// BM=128, BK=32, 4 waves (wave w -> rows w*32..w*32+31, all 128 cols).
// global_load_lds double-buffer pipeline, raw s_barrier + counted vmcnt.
// LDS layout: [row][32-elem] linear with 16B-slot XOR swizzle, realized by
// pre-swizzling the GLOBAL source addresses (LDS dest stays linear).
template <int K, bool AFP32>
__device__ __forceinline__ void gemm_body(const void* __restrict__ Ap,
                                          const ushort* __restrict__ Wt,
                                          ushort* __restrict__ C, int M, int blk) {
    constexpr int NT = K / 32;
    constexpr int ABYTES = AFP32 ? 128 * 32 * 4 : 128 * 32 * 2;
    constexpr int WBYTES = 128 * 32 * 2;
    __shared__ char smem[2 * (ABYTES + WBYTES)];

    int tid = threadIdx.x;
    int row0 = blk * 128;
    int wid = tid >> 6, lane = tid & 63;
    int wm = wid * 32;
    int lm = lane & 15, lk8 = (lane >> 4) * 8;

    const float* Af = (const float*)Ap;
    const ushort* Ab16 = (const ushort*)Ap;

    f32x4 acc[8][2];
#pragma unroll
    for (int q = 0; q < 8; q++)
#pragma unroll
        for (int r = 0; r < 2; r++) acc[q][r] = (f32x4){0.f, 0.f, 0.f, 0.f};

    // DMA staging: per wave-call, HW writes LDS at (uniform base + lane*16).
    auto stage = [&](int bi, int k0) {
        char* Abase = smem + bi * ABYTES;
        char* Wbase = smem + 2 * ABYTES + bi * WBYTES;
        if (AFP32) {
            // A fp32 tile: 16KB = 16 wave-calls; rows 128B = 8 slots of 16B.
#pragma unroll
            for (int j = 0; j < 4; j++) {
                int c = wid * 4 + j;
                int rp = c * 8 + (lane >> 3);
                int sl = (lane & 7) ^ (rp & 7);  // inverse-swizzled source slot
                int gr2 = row0 + rp; if (gr2 >= M) gr2 = M - 1;
                GLDS16(Af + (size_t)gr2 * K + k0 + sl * 4, Abase + c * 1024);
            }
        } else {
            // A bf16 tile: 8KB = 8 wave-calls; rows 64B = 4 slots of 16B.
#pragma unroll
            for (int j = 0; j < 2; j++) {
                int c = wid * 2 + j;
                int rp = c * 16 + (lane >> 2);
                int sl = (lane & 3) ^ (rp & 3);
                int gr2 = row0 + rp; if (gr2 >= M) gr2 = M - 1;
                GLDS16(Ab16 + (size_t)gr2 * K + k0 + sl * 8, Abase + c * 1024);
            }
        }
        // W bf16 tile: 8KB = 8 wave-calls.
#pragma unroll
        for (int j = 0; j < 2; j++) {
            int c = wid * 2 + j;
            int rp = c * 16 + (lane >> 2);
            int sl = (lane & 3) ^ (rp & 3);
            GLDS16(Wt + (size_t)rp * K + k0 + sl * 8, Wbase + c * 1024);
        }
    };

    stage(0, 0);

    int cur = 0;
    for (int t = 0; t < NT; t++) {
        if (t + 1 < NT) {
            stage((t + 1) & 1, (t + 1) * 32);
            // wait for tile t only; tile t+1's loads stay in flight
            if (AFP32) asm volatile("s_waitcnt vmcnt(6)" ::: "memory");
            else       asm volatile("s_waitcnt vmcnt(4)" ::: "memory");
        } else {
            asm volatile("s_waitcnt vmcnt(0)" ::: "memory");
        }
        __builtin_amdgcn_s_barrier();  // buf[cur] DMA'd by all waves

        char* Abase = smem + cur * ABYTES;
        char* Wbase = smem + 2 * ABYTES + cur * WBYTES;
        bf16x8 xf[2], wf[8];
        if (AFP32) {
#pragma unroll
            for (int r = 0; r < 2; r++) {
                int r_ = wm + r * 16 + lm;
                int s0 = lk8 >> 2;  // 16B slot (4 fp32) pair s0, s0+1
                f32x4 a0 = *(const f32x4*)(Abase + r_ * 128 + (((s0)     ^ (r_ & 7)) << 4));
                f32x4 a1 = *(const f32x4*)(Abase + r_ * 128 + (((s0 + 1) ^ (r_ & 7)) << 4));
                uint4 u;
                u.x = pk2bf(a0[0], a0[1]);
                u.y = pk2bf(a0[2], a0[3]);
                u.z = pk2bf(a1[0], a1[1]);
                u.w = pk2bf(a1[2], a1[3]);
                xf[r] = *(bf16x8*)&u;
            }
        } else {
#pragma unroll
            for (int r = 0; r < 2; r++) {
                int r_ = wm + r * 16 + lm;
                int s = lk8 >> 3;
                uint4 u = *(const uint4*)(Abase + r_ * 64 + ((s ^ (r_ & 3)) << 4));
                xf[r] = *(bf16x8*)&u;
            }
        }
#pragma unroll
        for (int q = 0; q < 8; q++) {
            int n_ = q * 16 + lm;
            int s = lk8 >> 3;
            uint4 u = *(const uint4*)(Wbase + n_ * 64 + ((s ^ (n_ & 3)) << 4));
            wf[q] = *(bf16x8*)&u;
        }
#pragma unroll
        for (int q = 0; q < 8; q++)
#pragma unroll
            for (int r = 0; r < 2; r++)
                acc[q][r] = __builtin_amdgcn_mfma_f32_16x16x32_bf16(wf[q], xf[r], acc[q][r], 0, 0, 0);

        asm volatile("" ::: "memory");     // fence: reads can't sink past barrier
        __builtin_amdgcn_s_barrier();      // all waves done reading buf[cur]
        cur ^= 1;
    }

    int cn4 = (lane >> 4) * 4;
#pragma unroll
    for (int r = 0; r < 2; r++) {
        int m = row0 + wm + r * 16 + lm;
        if (m < M) {
#pragma unroll
            for (int q = 0; q < 8; q++) {
                int n = q * 16 + cn4;
                uint2 o;
                o.x = (uint)f2bf(acc[q][r][0]) | ((uint)f2bf(acc[q][r][1]) << 16);
                o.y = (uint)f2bf(acc[q][r][2]) | ((uint)f2bf(acc[q][r][3]) << 16);
                *(uint2*)(C + (size_t)m * 128 + n) = o;
            }
        }
    }
}

// mega kernel 1: blocks [0,DEG_BLKS) count degrees; rest do GEMM1
__global__ __launch_bounds__(256) void k_mega1(const float* __restrict__ x,
                                               const ushort* __restrict__ Wt1,
                                               ushort* __restrict__ C,
                                               const int* __restrict__ dst,
                                               int* __restrict__ deg) {
    if (blockIdx.x < DEG_BLKS) {
        int i = blockIdx.x * 256 + threadIdx.x;
        int stride = DEG_BLKS * 256;
        for (; i < EE; i += stride) atomicAdd(&deg[dst[i]], 1);
    } else {
        gemm_body<IND, true>(x, Wt1, C, NN, blockIdx.x - DEG_BLKS);
    }
}

__global__ __launch_bounds__(256) void k_gemm2(const ushort* __restrict__ A,
                                               const ushort* __restrict__ Wt,
                                               ushort* __restrict__ C) {
    gemm_body<HIDD, false>(A, Wt, C, NN, blockIdx.x);
}

// ---------------- aggregation over bf16 h ----------------
// One node per wave. Half-wave edge pairing: lanes 0-31 even edges, 32-63 odd;
// each lane loads uint2 (4 dims), 32 lanes cover the 128-dim row.
template <bool OUTF32>
__global__ __launch_bounds__(256) void k_agg(const ushort* __restrict__ h,
                                             const int* __restrict__ rs,
                                             const int2* __restrict__ ew,
                                             const float* __restrict__ dinv,
                                             const float* __restrict__ bias,
                                             void* __restrict__ yv) {
    int node = blockIdx.x * 4 + (threadIdx.x >> 6);
    int lane = threadIdx.x & 63;
    if (node >= NN) return;
    int half = lane >> 5, c = lane & 31;
    const uint2* h64 = (const uint2*)h;

    float acc0 = 0.f, acc1 = 0.f, acc2 = 0.f, acc3 = 0.f;
    if (half == 0) {  // self-loop term, lower half only
        float dv = dinv[node];
        uint2 sv = h64[(size_t)node * 32 + c];
        acc0 = __uint_as_float(sv.x << 16) * dv;
        acc1 = __uint_as_float(sv.x & 0xffff0000u) * dv;
        acc2 = __uint_as_float(sv.y << 16) * dv;
        acc3 = __uint_as_float(sv.y & 0xffff0000u) * dv;
    }

    int e = rs[node], e1 = rs[node + 1];

#define EL(i) int2 p##i = ew[e + 2 * i + half]; \
              uint2 g##i = h64[(size_t)(uint)p##i.x * 32 + c];
#define EA(i) { float w##i = __int_as_float(p##i.y); \
    acc0 += w##i * __uint_as_float(g##i.x << 16); \
    acc1 += w##i * __uint_as_float(g##i.x & 0xffff0000u); \
    acc2 += w##i * __uint_as_float(g##i.y << 16); \
    acc3 += w##i * __uint_as_float(g##i.y & 0xffff0000u); }

    for (; e + 16 <= e1; e += 16) {  // 8 pairs = 16 edges in flight
        EL(0) EL(1) EL(2) EL(3) EL(4) EL(5) EL(6) EL(7)
        EA(0) EA(1) EA(2) EA(3) EA(4) EA(5) EA(6) EA(7)
    }
    for (; e + 4 <= e1; e += 4) {    // 2 pairs = 4 edges
        EL(0) EL(1)
        EA(0) EA(1)
    }
    if (e + 2 <= e1) {               // 1 pair
        EL(0)
        EA(0)
        e += 2;
    }
    if (e < e1 && half == 0) {       // final odd edge, lower half only
        int2 p = ew[e];
        uint2 g = h64[(size_t)(uint)p.x * 32 + c];
        float w = __int_as_float(p.y);
        acc0 += w * __uint_as_float(g.x << 16);
        acc1 += w * __uint_as_float(g.x & 0xffff0000u);
        acc2 += w * __uint_as_float(g.y << 16);
        acc3 += w * __uint_as_float(g.y & 0xffff0000u);
    }
#undef EL
#undef EA

    // merge halves
    acc0 += __shfl_xor(acc0, 32, 64);
    acc1 += __shfl_xor(acc1, 32, 64);
    acc2 += __shfl_xor(acc2, 32, 64);
    acc3 += __shfl_xor(acc3, 32, 64);

    if (half == 0) {
        float4 bv = *(const float4*)(bias + c * 4);
        acc0 = fmaxf(acc0 + bv.x, 0.f);
        acc1 = fmaxf(acc1 + bv.y, 0.f);
        acc2 = fmaxf(acc2 + bv.z, 0.f);
        acc3 = fmaxf(acc3 + bv.w, 0.f);
        if (OUTF32) {
            *(float4*)((float*)yv + (size_t)node * 128 + c * 4) =
                make_float4(acc0, acc1, acc2, acc3);
        } else {
            uint2 o;
            o.x = (uint)f2bf(acc0) | ((uint)f2bf(acc1) << 16);
            o.y = (uint)f2bf(acc2) | ((uint)f2bf(acc3) << 16);
            *(uint2*)((ushort*)yv + (size_t)node * 128 + c * 4) = o;
        }
    }
}

// ---------------- head: out[N][16] = emb[N][128] @ Wl[128][16] + bl ----------------
__global__ __launch_bounds__(256) void k_out(const float* __restrict__ emb,
                                             const float* __restrict__ Wl,
                                             const float* __restrict__ bl,
                                             float* __restrict__ out) {
    __shared__ float wl_s[128 * 16];
    __shared__ float es[16][129];
    int tid = threadIdx.x;
    int row0 = blockIdx.x * 16;
#pragma unroll
    for (int p = 0; p < 8; p++) wl_s[p * 256 + tid] = Wl[p * 256 + tid];
#pragma unroll
    for (int p = 0; p < 8; p++) {
        int idx = p * 256 + tid;
        int r = idx >> 7, c = idx & 127;
        int gr = row0 + r;
        es[r][c] = (gr < NN) ? emb[(size_t)gr * 128 + c] : 0.0f;
    }
    __syncthreads();
    int r = tid >> 4, o = tid & 15;
    float acc = bl[o];
#pragma unroll
    for (int k = 0; k < 128; k++) acc += es[r][k] * wl_s[k * 16 + o];
    int gr = row0 + r;
    if (gr < NN) out[(size_t)gr * 16 + o] = acc;
}

extern "C" void kernel_launch(void* const* d_in, const int* in_sizes, int n_in,
                              void* d_out, int out_size, void* d_ws, size_t ws_size,
                              hipStream_t stream) {
    const float* x  = (const float*)d_in[0];
    const int* ei   = (const int*)d_in[1];  // [2][E]: row0=src, row1=dst
    const float* W1 = (const float*)d_in[2];
    const float* b1 = (const float*)d_in[3];
    const float* W2 = (const float*)d_in[4];
    const float* b2 = (const float*)d_in[5];
    const float* Wl = (const float*)d_in[6];
    const float* bl = (const float*)d_in[7];
    const int* src = ei;
    const int* dst = ei + EE;

    float* outp = (float*)d_out;             // [N][16]
    float* emb  = outp + (size_t)NN * OUTD;  // [N][128] fp32

    int2* ew    = (int2*)d_ws;                        // E pairs (src, w)
    ushort* h_a = (ushort*)(ew + EE);                 // N*128 bf16
    ushort* h_b = h_a + (size_t)NN * 128;             // N*128 bf16
    ushort* Wt1 = h_b + (size_t)NN * 128;             // 128*512 bf16
    ushort* Wt2 = Wt1 + 128 * 512;                    // 128*128 bf16
    int* deg    = (int*)(Wt2 + 128 * 128);
    float* dis  = (float*)(deg + NN);
    float* dinv = dis + NN;
    int* incl   = (int*)(dinv + NN);
    int* rs     = incl + NN;                          // N+1
    int* cursor = rs + NN + 8;
    int* bsum   = cursor + NN;
    int* boff   = bsum + 512;

    const int NB_N = (NN + 255) / 256;  // 391

    hipMemsetAsync(deg, 0, (size_t)NN * sizeof(int), stream);
    k_prep<<<320, 256, 0, stream>>>(W1, W2, Wt1, Wt2);
    // gemm1 (x@W1 -> h_a bf16)  ||  degree count
    k_mega1<<<DEG_BLKS + GEMM_BLKS, 256, 0, stream>>>(x, Wt1, h_a, dst, deg);
    k_scan_local<<<NB_N, 256, 0, stream>>>(deg, incl, bsum);
    k_scan_bsum<<<1, 512, 0, stream>>>(bsum, boff, NB_N);
    k_scan_final<<<NB_N, 256, 0, stream>>>(incl, deg, boff, rs, cursor, dis, dinv);
    k_fill<<<2048, 256, 0, stream>>>(src, dst, dis, cursor, ew);

    // layer 1 agg: h_b = bf16(relu(agg(h_a) + b1))
    k_agg<false><<<(NN + 3) / 4, 256, 0, stream>>>(h_a, rs, ew, dinv, b1, h_b);
    // layer 2: h_a = bf16(h_b @ W2); emb = fp32(relu(agg(h_a) + b2))
    k_gemm2<<<GEMM_BLKS, 256, 0, stream>>>(h_b, Wt2, h_a);
    k_agg<true><<<(NN + 3) / 4, 256, 0, stream>>>(h_a, rs, ew, dinv, b2, emb);
    // head
    k_out<<<(NN + 15) / 16, 256, 0, stream>>>(emb, Wl, bl, outp);
}